// Round 1
// baseline (210.935 us; speedup 1.0000x reference)
//
#include <hip/hip_runtime.h>
#include <stdint.h>

#define KNN 16

typedef float vfloat4 __attribute__((ext_vector_type(4)));

// Map float to a uint32 whose unsigned order matches the float order
// (handles tiny negative dists from fp rounding).
__device__ __forceinline__ uint32_t fkey(float f) {
    uint32_t u = __float_as_uint(f);
    return (u & 0x80000000u) ? ~u : (u | 0x80000000u);
}

// u64 broadcast from wave-uniform lane l: two v_readlane (no DS-pipe traffic,
// unlike __shfl which lowers to 2x ds_bpermute_b32).
__device__ __forceinline__ unsigned long long bcast64(unsigned long long x, int l) {
    const uint32_t lo = (uint32_t)__builtin_amdgcn_readlane((int)(uint32_t)x, l);
    const uint32_t hi = (uint32_t)__builtin_amdgcn_readlane((int)(uint32_t)(x >> 32), l);
    return ((unsigned long long)hi << 32) | lo;
}

// u64 lane shift-up-by-1 within each 16-lane DPP row (row_shr:1 = 0x111).
// Lanes 1..15 get lane-1..14's value — identical to __shfl_up(x,1) there;
// lane 0 gets 0 (bound_ctrl), which callers mask via an explicit lane==0
// select; lanes >=16 are discarded by the lane<16 list guard. VALU-only.
__device__ __forceinline__ unsigned long long shup1_64(unsigned long long x) {
    const uint32_t lo = (uint32_t)__builtin_amdgcn_update_dpp(
        0, (int)(uint32_t)x, 0x111, 0xF, 0xF, true);
    const uint32_t hi = (uint32_t)__builtin_amdgcn_update_dpp(
        0, (int)(uint32_t)(x >> 32), 0x111, 0xF, 0xF, true);
    return ((unsigned long long)hi << 32) | lo;
}

// Pack xyz_prev into (x, y, z, r2) float4 rows. r2 uses the exact fp32 op
// order of the reference (verified absmax 0 in R1-R4, R6-R9), so downstream
// distances are bit-identical.
__global__ __launch_bounds__(256) void prep_kernel(
    const float* __restrict__ xyz_prev, vfloat4* __restrict__ P, int n_prev)
{
    const int i = blockIdx.x * 256 + threadIdx.x;
    if (i >= n_prev) return;
    const float x = xyz_prev[3 * i + 0];
    const float y = xyz_prev[3 * i + 1];
    const float z = xyz_prev[3 * i + 2];
    const float r2 = __fadd_rn(__fadd_rn(__fmul_rn(x, x), __fmul_rn(y, y)),
                               __fmul_rn(z, z));
    vfloat4 v = {x, y, z, r2};
    P[i] = v;
}

// TWO waves per query (was one). Each wave runs the R7-verified structure
// (global 8-deep load batching, per-t ballot + serial insert into the
// wave-distributed sorted top-16 in lanes 0..15; u64 keys
// fkey(dist)<<32|idx == jax.lax.top_k stable order; tau = lane-15 key =
// EXACT running 16th-best of that wave's half-range) over HALF of n_prev,
// then the two sorted 16-lists are merged exactly with a 5-stage bitonic
// merge. Rationale: knn was ~10x above both its VALU floor (~12us) and its
// L2-read floor (~15us) -> latency/serial-chain bound at 4 waves/SIMD.
// This doubles occupancy AND halves the serial ballot-insert chain.
__global__ __launch_bounds__(256) void knn_kernel(
    const vfloat4* __restrict__ P, const float* __restrict__ xyz_cur,
    int* __restrict__ knn_idx, int n_prev, int n_cur)
{
    __shared__ unsigned long long smem[2][2][KNN];  // [query-slot][half][rank]
    const int lane = threadIdx.x & 63;
    const int qq   = threadIdx.x >> 7;        // query slot in block (0..1)
    const int h    = (threadIdx.x >> 6) & 1;  // half-range index (0..1)
    const int q    = blockIdx.x * 2 + qq;
    const bool active = q < n_cur;            // wave-uniform

    if (active) {
        const float qx = xyz_cur[3 * q + 0];
        const float qy = xyz_cur[3 * q + 1];
        const float qz = xyz_cur[3 * q + 2];
        // q2 is a per-query constant (cannot change the argsort); same op order.
        const float q2 = __fadd_rn(__fadd_rn(__fmul_rn(qx, qx), __fmul_rn(qy, qy)),
                                   __fmul_rn(qz, qz));

        // Half-range split: multiple of 64 so the iteration structure is clean.
        const int half_len = ((n_prev + 127) >> 7) << 6;
        const int base = h * half_len;
        const int end  = min((h + 1) * half_len, n_prev);  // keys valid iff r < end

        // ---- warmup: bitonic sort of this wave's first 64 candidates ----
        unsigned long long v;
        {
            const int r = base + lane;
            const vfloat4 p = P[r < n_prev ? r : 0];
            const float cr = __fmaf_rn(p.z, qz, __fmaf_rn(p.y, qy, __fmul_rn(p.x, qx)));
            const float dist = __fsub_rn(__fadd_rn(q2, p.w), __fmul_rn(2.0f, cr));
            v = (r < end)
                ? (((unsigned long long)fkey(dist) << 32) | (uint32_t)r)
                : ~0ull;
        }
#pragma unroll
        for (int k = 2; k <= 64; k <<= 1) {
#pragma unroll
            for (int j = k >> 1; j > 0; j >>= 1) {
                const unsigned long long o = __shfl_xor(v, j, 64);
                const bool keepMin = (((lane & k) == 0) == ((lane & j) == 0));
                const bool omin = o < v;
                v = (keepMin == omin) ? o : v;  // keepMin ? min(v,o) : max(v,o)
            }
        }
        unsigned long long lkey = (lane < KNN) ? v : ~0ull;
        unsigned long long tau = bcast64(lkey, 15);  // EXACT running 16th-best (this half)

        const int count = end - base;
        const int n_iter = count > 0 ? ((count + 63) >> 6) : 0;  // wave-uniform
        int t = 1;
        // main: groups of 8 iterations, loads issued up front (8-deep MLP),
        // then each t processed with the verified ballot+insert body.
        for (; t + 7 < n_iter; t += 8) {
            vfloat4 pv[8];
#pragma unroll
            for (int u = 0; u < 8; ++u) {
                const int r = base + ((t + u) << 6) + lane;
                pv[u] = P[r < n_prev ? r : 0];
            }
#pragma unroll
            for (int u = 0; u < 8; ++u) {
                const int r = base + ((t + u) << 6) + lane;
                const vfloat4 p = pv[u];
                const float cr = __fmaf_rn(p.z, qz, __fmaf_rn(p.y, qy, __fmul_rn(p.x, qx)));
                const float dist = __fsub_rn(__fadd_rn(q2, p.w), __fmul_rn(2.0f, cr));
                const unsigned long long key = (r < end)
                    ? (((unsigned long long)fkey(dist) << 32) | (uint32_t)r)
                    : ~0ull;
                unsigned long long mask = __ballot(key < tau);
                while (mask) {  // wave-uniform
                    const int b = (int)__builtin_ctzll(mask);
                    mask &= mask - 1;
                    const unsigned long long bk = bcast64(key, b);
                    if (bk < tau) {  // re-check: tau may have tightened (uniform)
                        const unsigned long long sh = shup1_64(lkey);
                        unsigned long long nk;
                        if (lkey < bk) nk = lkey;                    // stays
                        else nk = (lane == 0 || sh < bk) ? bk : sh;  // insert/shift
                        tau = bcast64(nk, 15);  // nk computed by all 64 lanes
                        if (lane < KNN) lkey = nk;
                    }
                }
            }
        }
        // tail: identical single-t body
        for (; t < n_iter; ++t) {
            const int r = base + (t << 6) + lane;
            const vfloat4 p = P[r < n_prev ? r : 0];
            const float cr = __fmaf_rn(p.z, qz, __fmaf_rn(p.y, qy, __fmul_rn(p.x, qx)));
            const float dist = __fsub_rn(__fadd_rn(q2, p.w), __fmul_rn(2.0f, cr));
            const unsigned long long key = (r < end)
                ? (((unsigned long long)fkey(dist) << 32) | (uint32_t)r)
                : ~0ull;
            unsigned long long mask = __ballot(key < tau);
            while (mask) {
                const int b = (int)__builtin_ctzll(mask);
                mask &= mask - 1;
                const unsigned long long bk = bcast64(key, b);
                if (bk < tau) {
                    const unsigned long long sh = shup1_64(lkey);
                    unsigned long long nk;
                    if (lkey < bk) nk = lkey;
                    else nk = (lane == 0 || sh < bk) ? bk : sh;
                    tau = bcast64(nk, 15);
                    if (lane < KNN) lkey = nk;
                }
            }
        }

        if (lane < KNN) smem[qq][h][lane] = lkey;
    }

    __syncthreads();

    // ---- exact merge of the two sorted half-range top-16 lists ----
    // A ascending in lanes 0..15, B descending in lanes 16..31 -> bitonic
    // sequence of 32 -> 5 compare-exchange stages -> lanes 0..15 hold the
    // global top-16 in ascending key order (keys are unique: idx embedded).
    if (active && h == 0) {
        unsigned long long v = ~0ull;
        if (lane < 16)      v = smem[qq][0][lane];
        else if (lane < 32) v = smem[qq][1][31 - lane];
#pragma unroll
        for (int j = 16; j > 0; j >>= 1) {
            const unsigned long long o = __shfl_xor(v, j, 64);
            const bool keepMin = ((lane & j) == 0);
            const bool omin = o < v;
            v = (keepMin == omin) ? o : v;
        }
        if (lane < KNN)
            knn_idx[q * KNN + lane] = (int)(v & 0xffffffffu);
    }
}

// R7-verified combine, verbatim: one wave per (query, neighbor-group-of-4).
// Coverage: w in [0, 4*n_cur) -> q = w>>2, jg = (w&3)*4; rows q*16+jg+{0..3}
// — every output row exactly once. Nontemporal stores keep the 134 MB write
// stream from evicting the 8 MB gather table out of L2/LLC.
__global__ __launch_bounds__(256) void combine_kernel(
    const float* __restrict__ feat_prev, const float* __restrict__ feat_cur,
    const int* __restrict__ knn_idx, float* __restrict__ out,
    int n_cur, int c4)
{
    const int w = blockIdx.x * 4 + (threadIdx.x >> 6);
    const int lane = threadIdx.x & 63;
    const int q = w >> 2;
    const int jg = (w & 3) * 4;
    if (q >= n_cur) return;

    int nb[4];
#pragma unroll
    for (int j = 0; j < 4; ++j)
        nb[j] = knn_idx[q * KNN + jg + j];

    const vfloat4* pbase = (const vfloat4*)feat_prev;
    const vfloat4* crow  = (const vfloat4*)feat_cur + (size_t)q * c4;
    const int c8 = 2 * c4;

    for (int i = lane; i < c4; i += 64) {
        const vfloat4 c = crow[i];
        vfloat4 p[4];
#pragma unroll
        for (int j = 0; j < 4; ++j)
            p[j] = pbase[(size_t)nb[j] * c4 + i];

#pragma unroll
        for (int j = 0; j < 4; ++j) {
            vfloat4* orow = (vfloat4*)out + (size_t)(q * KNN + jg + j) * c8;
            __builtin_nontemporal_store(p[j] - c, orow + i);
            __builtin_nontemporal_store(c, orow + c4 + i);
        }
    }
}

extern "C" void kernel_launch(void* const* d_in, const int* in_sizes, int n_in,
                              void* d_out, int out_size, void* d_ws, size_t ws_size,
                              hipStream_t stream) {
    const float* xyz_prev  = (const float*)d_in[0];
    const float* xyz_cur   = (const float*)d_in[1];
    const float* feat_prev = (const float*)d_in[2];
    const float* feat_cur  = (const float*)d_in[3];
    float* out = (float*)d_out;

    const int n_prev = in_sizes[0] / 3;
    const int n_cur  = in_sizes[1] / 3;
    const int C      = in_sizes[2] / n_prev;   // 256

    // d_ws layout: [0, 16*n_prev) packed (x,y,z,r2) table; then knn indices.
    vfloat4* P = (vfloat4*)d_ws;
    int* knn = (int*)((char*)d_ws + (size_t)n_prev * sizeof(vfloat4));

    prep_kernel<<<(n_prev + 255) / 256, 256, 0, stream>>>(xyz_prev, P, n_prev);

    // 2 queries per block, 2 waves per query (half-range split + merge).
    const int knn_blocks = (n_cur + 1) / 2;
    knn_kernel<<<knn_blocks, 256, 0, stream>>>(P, xyz_cur, knn, n_prev, n_cur);

    const int n_waves = n_cur * 4;             // 4 neighbor-rows per wave
    combine_kernel<<<(n_waves + 3) / 4, 256, 0, stream>>>(feat_prev, feat_cur,
                                                          knn, out, n_cur, C / 4);
}

// Round 2
// 206.333 us; speedup vs baseline: 1.0223x; 1.0223x over previous
//
#include <hip/hip_runtime.h>
#include <stdint.h>

#define KNN 16

typedef float vfloat4 __attribute__((ext_vector_type(4)));

// Map float to a uint32 whose unsigned order matches the float order
// (handles tiny negative dists from fp rounding).
__device__ __forceinline__ uint32_t fkey(float f) {
    uint32_t u = __float_as_uint(f);
    return (u & 0x80000000u) ? ~u : (u | 0x80000000u);
}

// Inverse of fkey on the high word of a u64 key -> the float dist.
// Sentinel keys (~0ull slots, hi == 0xFFFFFFFF) map to +inf so that the
// float ballot "dist < tauf" admits everything while the list isn't full.
__device__ __forceinline__ float inv_fkey_hi(unsigned long long key) {
    const uint32_t k = (uint32_t)(key >> 32);
    if (k == 0xFFFFFFFFu) return __builtin_inff();
    const uint32_t u = (k & 0x80000000u) ? (k ^ 0x80000000u) : ~k;
    return __uint_as_float(u);
}

// u64 broadcast from wave-uniform lane l: two v_readlane (no DS-pipe traffic,
// unlike __shfl which lowers to 2x ds_bpermute_b32).
__device__ __forceinline__ unsigned long long bcast64(unsigned long long x, int l) {
    const uint32_t lo = (uint32_t)__builtin_amdgcn_readlane((int)(uint32_t)x, l);
    const uint32_t hi = (uint32_t)__builtin_amdgcn_readlane((int)(uint32_t)(x >> 32), l);
    return ((unsigned long long)hi << 32) | lo;
}

// u64 lane shift-up-by-1 within each 16-lane DPP row (row_shr:1 = 0x111).
// Lanes 1..15 get lane-1..14's value; lane 0 gets 0 (bound_ctrl), masked by
// callers via an explicit lane==0 select; lanes >=16 are discarded by the
// lane<16 list guard. VALU-only.
__device__ __forceinline__ unsigned long long shup1_64(unsigned long long x) {
    const uint32_t lo = (uint32_t)__builtin_amdgcn_update_dpp(
        0, (int)(uint32_t)x, 0x111, 0xF, 0xF, true);
    const uint32_t hi = (uint32_t)__builtin_amdgcn_update_dpp(
        0, (int)(uint32_t)(x >> 32), 0x111, 0xF, 0xF, true);
    return ((unsigned long long)hi << 32) | lo;
}

// Pack xyz_prev into (x, y, z, r2) float4 rows. r2 uses the exact fp32 op
// order of the reference (verified absmax 0 across prior rounds), so
// downstream distances are bit-identical.
__global__ __launch_bounds__(256) void prep_kernel(
    const float* __restrict__ xyz_prev, vfloat4* __restrict__ P, int n_prev)
{
    const int i = blockIdx.x * 256 + threadIdx.x;
    if (i >= n_prev) return;
    const float x = xyz_prev[3 * i + 0];
    const float y = xyz_prev[3 * i + 1];
    const float z = xyz_prev[3 * i + 2];
    const float r2 = __fadd_rn(__fadd_rn(__fmul_rn(x, x), __fmul_rn(y, y)),
                               __fmul_rn(z, z));
    vfloat4 v = {x, y, z, r2};
    P[i] = v;
}

// Two waves per query, each scanning half of n_prev with the verified
// ballot+serial-insert top-16 (u64 keys fkey(dist)<<32|idx == jax.lax.top_k
// stable order), then an exact 5-stage bitonic merge of the two sorted lists.
//
// R2 changes vs R1 (theory: VALU-issue-bound at 4 waves/SIMD):
//  (a) FLOAT ballot: the hot-loop test is a single v_cmp_lt_f32
//      (dist < tauf) instead of building the u64 key per lane per t.
//      EXACTNESS: candidates arrive in increasing idx order and ballot bits
//      are consumed low->high, so every current list entry has idx < the
//      candidate's idx; on a dist tie the candidate's key is therefore
//      ALWAYS larger -> key<tau  <=>  dist<tauf (strict). dist can never be
//      -0.0 (a-b with a>=+0 never rounds to -0 in RN), never NaN; sentinel
//      slots map to tauf=+inf. The insert path re-checks with exact u64 keys.
//  (b) no bounds predication in the main loop (iterations are provably full;
//      generic partial handled in a separate predicated tail).
//  (c) pv[4] batching + __launch_bounds__(256,8): VGPR <= 64 so occupancy
//      reaches 8 waves/SIMD (R1's pv[8] + u64 hot path pushed past 64 ->
//      4 waves/SIMD, which is why doubling wave count didn't help).
__global__ __launch_bounds__(256, 8) void knn_kernel(
    const vfloat4* __restrict__ P, const float* __restrict__ xyz_cur,
    int* __restrict__ knn_idx, int n_prev, int n_cur)
{
    __shared__ unsigned long long smem[2][2][KNN];  // [query-slot][half][rank]
    const int lane = threadIdx.x & 63;
    const int qq   = threadIdx.x >> 7;        // query slot in block (0..1)
    const int h    = (threadIdx.x >> 6) & 1;  // half-range index (0..1)
    const int q    = blockIdx.x * 2 + qq;
    const bool active = q < n_cur;            // wave-uniform

    if (active) {
        const float qx = xyz_cur[3 * q + 0];
        const float qy = xyz_cur[3 * q + 1];
        const float qz = xyz_cur[3 * q + 2];
        // q2 is a per-query constant (cannot change the argsort); same op order.
        const float q2 = __fadd_rn(__fadd_rn(__fmul_rn(qx, qx), __fmul_rn(qy, qy)),
                                   __fmul_rn(qz, qz));

        // Half-range split: multiple of 64 so the iteration structure is clean.
        const int half_len = ((n_prev + 127) >> 7) << 6;
        const int base = h * half_len;
        const int end  = min((h + 1) * half_len, n_prev);  // keys valid iff r < end
        const int cnt  = (end > base) ? (end - base) : 0;

        // ---- warmup: bitonic sort of this wave's first 64 candidates ----
        unsigned long long v;
        {
            const int r = base + lane;
            const vfloat4 p = P[r < n_prev ? r : 0];
            const float cr = __fmaf_rn(p.z, qz, __fmaf_rn(p.y, qy, __fmul_rn(p.x, qx)));
            const float dist = __fsub_rn(__fadd_rn(q2, p.w), __fmul_rn(2.0f, cr));
            v = (r < end)
                ? (((unsigned long long)fkey(dist) << 32) | (uint32_t)r)
                : ~0ull;
        }
#pragma unroll
        for (int k = 2; k <= 64; k <<= 1) {
#pragma unroll
            for (int j = k >> 1; j > 0; j >>= 1) {
                const unsigned long long o = __shfl_xor(v, j, 64);
                const bool keepMin = (((lane & k) == 0) == ((lane & j) == 0));
                const bool omin = o < v;
                v = (keepMin == omin) ? o : v;  // keepMin ? min(v,o) : max(v,o)
            }
        }
        unsigned long long lkey = (lane < KNN) ? v : ~0ull;
        unsigned long long tau = bcast64(lkey, 15);  // EXACT running 16th-best (this half)
        float tauf = inv_fkey_hi(tau);               // same value as a float dist

        const int n_full = cnt >> 6;   // full 64-candidate iterations (incl. t=0)
        int t = 1;
        // main: groups of 4 full iterations, loads issued up front (4-deep MLP).
        for (; t + 3 < n_full; t += 4) {
            vfloat4 pv[4];
#pragma unroll
            for (int u = 0; u < 4; ++u)
                pv[u] = P[base + ((t + u) << 6) + lane];
#pragma unroll
            for (int u = 0; u < 4; ++u) {
                const int rbase = base + ((t + u) << 6);
                const vfloat4 p = pv[u];
                const float cr = __fmaf_rn(p.z, qz, __fmaf_rn(p.y, qy, __fmul_rn(p.x, qx)));
                const float dist = __fsub_rn(__fadd_rn(q2, p.w), __fmul_rn(2.0f, cr));
                unsigned long long mask = __ballot(dist < tauf);
                while (mask) {  // wave-uniform
                    const int b = (int)__builtin_ctzll(mask);
                    mask &= mask - 1;
                    // rebuild lane b's exact u64 key uniformly: 1 readlane + fkey
                    const float bd = __uint_as_float(
                        (uint32_t)__builtin_amdgcn_readlane((int)__float_as_uint(dist), b));
                    const unsigned long long bk =
                        (((unsigned long long)fkey(bd)) << 32) | (uint32_t)(rbase + b);
                    if (bk < tau) {  // exact re-check: tau may have tightened
                        const unsigned long long sh = shup1_64(lkey);
                        unsigned long long nk;
                        if (lkey < bk) nk = lkey;                    // stays
                        else nk = (lane == 0 || sh < bk) ? bk : sh;  // insert/shift
                        tau = bcast64(nk, 15);  // nk computed by all 64 lanes
                        tauf = inv_fkey_hi(tau);
                        if (lane < KNN) lkey = nk;
                    }
                }
            }
        }
        // remaining full iterations, single-t body (still no predication)
        for (; t < n_full; ++t) {
            const int rbase = base + (t << 6);
            const vfloat4 p = P[rbase + lane];
            const float cr = __fmaf_rn(p.z, qz, __fmaf_rn(p.y, qy, __fmul_rn(p.x, qx)));
            const float dist = __fsub_rn(__fadd_rn(q2, p.w), __fmul_rn(2.0f, cr));
            unsigned long long mask = __ballot(dist < tauf);
            while (mask) {
                const int b = (int)__builtin_ctzll(mask);
                mask &= mask - 1;
                const float bd = __uint_as_float(
                    (uint32_t)__builtin_amdgcn_readlane((int)__float_as_uint(dist), b));
                const unsigned long long bk =
                    (((unsigned long long)fkey(bd)) << 32) | (uint32_t)(rbase + b);
                if (bk < tau) {
                    const unsigned long long sh = shup1_64(lkey);
                    unsigned long long nk;
                    if (lkey < bk) nk = lkey;
                    else nk = (lane == 0 || sh < bk) ? bk : sh;
                    tau = bcast64(nk, 15);
                    tauf = inv_fkey_hi(tau);
                    if (lane < KNN) lkey = nk;
                }
            }
        }
        // generic partial tail (never taken for n_prev % 128 == 0)
        if (n_full >= 1 && (cnt & 63)) {
            const int rbase = base + (n_full << 6);
            const int r = rbase + lane;
            const vfloat4 p = P[r < n_prev ? r : 0];
            const float cr = __fmaf_rn(p.z, qz, __fmaf_rn(p.y, qy, __fmul_rn(p.x, qx)));
            float dist = __fsub_rn(__fadd_rn(q2, p.w), __fmul_rn(2.0f, cr));
            if (r >= end) dist = __builtin_inff();   // excluded (inf < tauf never true)
            unsigned long long mask = __ballot(dist < tauf);
            while (mask) {
                const int b = (int)__builtin_ctzll(mask);
                mask &= mask - 1;
                const float bd = __uint_as_float(
                    (uint32_t)__builtin_amdgcn_readlane((int)__float_as_uint(dist), b));
                const unsigned long long bk =
                    (((unsigned long long)fkey(bd)) << 32) | (uint32_t)(rbase + b);
                if (bk < tau) {
                    const unsigned long long sh = shup1_64(lkey);
                    unsigned long long nk;
                    if (lkey < bk) nk = lkey;
                    else nk = (lane == 0 || sh < bk) ? bk : sh;
                    tau = bcast64(nk, 15);
                    tauf = inv_fkey_hi(tau);
                    if (lane < KNN) lkey = nk;
                }
            }
        }

        if (lane < KNN) smem[qq][h][lane] = lkey;
    }

    __syncthreads();

    // ---- exact merge of the two sorted half-range top-16 lists ----
    // A ascending in lanes 0..15, B descending in lanes 16..31 -> bitonic
    // sequence of 32 -> 5 compare-exchange stages -> lanes 0..15 hold the
    // global top-16 in ascending key order (keys are unique: idx embedded).
    if (active && h == 0) {
        unsigned long long v = ~0ull;
        if (lane < 16)      v = smem[qq][0][lane];
        else if (lane < 32) v = smem[qq][1][31 - lane];
#pragma unroll
        for (int j = 16; j > 0; j >>= 1) {
            const unsigned long long o = __shfl_xor(v, j, 64);
            const bool keepMin = ((lane & j) == 0);
            const bool omin = o < v;
            v = (keepMin == omin) ? o : v;
        }
        if (lane < KNN)
            knn_idx[q * KNN + lane] = (int)(v & 0xffffffffu);
    }
}

// R7-verified combine, verbatim: one wave per (query, neighbor-group-of-4).
// Coverage: w in [0, 4*n_cur) -> q = w>>2, jg = (w&3)*4; rows q*16+jg+{0..3}
// — every output row exactly once. Nontemporal stores keep the 134 MB write
// stream from evicting the 8 MB gather table out of L2/LLC.
__global__ __launch_bounds__(256) void combine_kernel(
    const float* __restrict__ feat_prev, const float* __restrict__ feat_cur,
    const int* __restrict__ knn_idx, float* __restrict__ out,
    int n_cur, int c4)
{
    const int w = blockIdx.x * 4 + (threadIdx.x >> 6);
    const int lane = threadIdx.x & 63;
    const int q = w >> 2;
    const int jg = (w & 3) * 4;
    if (q >= n_cur) return;

    int nb[4];
#pragma unroll
    for (int j = 0; j < 4; ++j)
        nb[j] = knn_idx[q * KNN + jg + j];

    const vfloat4* pbase = (const vfloat4*)feat_prev;
    const vfloat4* crow  = (const vfloat4*)feat_cur + (size_t)q * c4;
    const int c8 = 2 * c4;

    for (int i = lane; i < c4; i += 64) {
        const vfloat4 c = crow[i];
        vfloat4 p[4];
#pragma unroll
        for (int j = 0; j < 4; ++j)
            p[j] = pbase[(size_t)nb[j] * c4 + i];

#pragma unroll
        for (int j = 0; j < 4; ++j) {
            vfloat4* orow = (vfloat4*)out + (size_t)(q * KNN + jg + j) * c8;
            __builtin_nontemporal_store(p[j] - c, orow + i);
            __builtin_nontemporal_store(c, orow + c4 + i);
        }
    }
}

extern "C" void kernel_launch(void* const* d_in, const int* in_sizes, int n_in,
                              void* d_out, int out_size, void* d_ws, size_t ws_size,
                              hipStream_t stream) {
    const float* xyz_prev  = (const float*)d_in[0];
    const float* xyz_cur   = (const float*)d_in[1];
    const float* feat_prev = (const float*)d_in[2];
    const float* feat_cur  = (const float*)d_in[3];
    float* out = (float*)d_out;

    const int n_prev = in_sizes[0] / 3;
    const int n_cur  = in_sizes[1] / 3;
    const int C      = in_sizes[2] / n_prev;   // 256

    // d_ws layout: [0, 16*n_prev) packed (x,y,z,r2) table; then knn indices.
    vfloat4* P = (vfloat4*)d_ws;
    int* knn = (int*)((char*)d_ws + (size_t)n_prev * sizeof(vfloat4));

    prep_kernel<<<(n_prev + 255) / 256, 256, 0, stream>>>(xyz_prev, P, n_prev);

    // 2 queries per block, 2 waves per query (half-range split + merge).
    const int knn_blocks = (n_cur + 1) / 2;
    knn_kernel<<<knn_blocks, 256, 0, stream>>>(P, xyz_cur, knn, n_prev, n_cur);

    const int n_waves = n_cur * 4;             // 4 neighbor-rows per wave
    combine_kernel<<<(n_waves + 3) / 4, 256, 0, stream>>>(feat_prev, feat_cur,
                                                          knn, out, n_cur, C / 4);
}